// Round 1
// baseline (681.825 us; speedup 1.0000x reference)
//
#include <hip/hip_runtime.h>
#include <stdint.h>

#define DH 128

typedef __attribute__((ext_vector_type(8))) short short8;
typedef __attribute__((ext_vector_type(4))) float f32x4;

__device__ __forceinline__ unsigned short f2bf(float f) {
  union { float f; unsigned u; } v; v.f = f;
  unsigned r = v.u + 0x7fffu + ((v.u >> 16) & 1u);
  return (unsigned short)(r >> 16);
}
__device__ __forceinline__ float bf2f(unsigned short s) {
  union { unsigned u; float f; } v; v.u = ((unsigned)s) << 16;
  return v.f;
}

// ---------- K0: pack 6 weight matrices [128x128] f32 -> bf16 MFMA B-frag layout
// layout index: ((mat*4 + kt)*8 + nt)*64*8 + lane*8 + j
// frag element j of lane: B[k = kt*32 + (lane>>4)*8 + j][n = nt*16 + (lane&15)]
__global__ __launch_bounds__(256) void pack_weights(
    const float* __restrict__ wz, const float* __restrict__ uz,
    const float* __restrict__ wr, const float* __restrict__ ur,
    const float* __restrict__ w,  const float* __restrict__ u,
    unsigned short* __restrict__ wf) {
  int t = blockIdx.x * 256 + threadIdx.x;
  if (t >= 6 * 16384) return;
  int mat = t >> 14;
  int r = t & 16383;
  int j = r & 7;
  int lane = (r >> 3) & 63;
  int nt = (r >> 9) & 7;
  int kt = (r >> 12) & 3;
  int k = kt * 32 + ((lane >> 4) << 3) + j;
  int n = nt * 16 + (lane & 15);
  const float* m_;
  switch (mat) {
    case 0: m_ = wz; break; case 1: m_ = uz; break; case 2: m_ = wr; break;
    case 3: m_ = ur; break; case 4: m_ = w;  break; default: m_ = u;
  }
  wf[t] = f2bf(m_[k * DH + n]);
}

// ---------- K2 chain: CSR build by dst ----------
__global__ __launch_bounds__(256) void zero_counts(int* __restrict__ cnt, int N) {
  int i = blockIdx.x * 256 + threadIdx.x;
  if (i < N) cnt[i] = 0;
}
__global__ __launch_bounds__(256) void count_deg(const int* __restrict__ dst,
                                                 int* __restrict__ cnt, int E) {
  int i = blockIdx.x * 256 + threadIdx.x;
  if (i < E) atomicAdd(&cnt[dst[i]], 1);
}
__global__ __launch_bounds__(256) void block_reduce(const int* __restrict__ cnt,
                                                    int* __restrict__ bsum, int N) {
  __shared__ int sd[256];
  int t = threadIdx.x;
  int i = blockIdx.x * 256 + t;
  sd[t] = (i < N) ? cnt[i] : 0;
  __syncthreads();
  for (int d = 128; d > 0; d >>= 1) {
    if (t < d) sd[t] += sd[t + d];
    __syncthreads();
  }
  if (t == 0) bsum[blockIdx.x] = sd[0];
}
// single block: exclusive-scan bsum[0..nb) in place (nb <= 512), write offs[N]=E
__global__ __launch_bounds__(512) void scan_bsums(int* __restrict__ bsum, int nb,
                                                  int* __restrict__ offs, int N, int E) {
  __shared__ int sd[512];
  int t = threadIdx.x;
  int v = (t < nb) ? bsum[t] : 0;
  sd[t] = v;
  __syncthreads();
  for (int d = 1; d < 512; d <<= 1) {
    int x = sd[t];
    if (t >= d) x += sd[t - d];
    __syncthreads();
    sd[t] = x;
    __syncthreads();
  }
  if (t < nb) bsum[t] = sd[t] - v;  // exclusive
  if (t == 0) offs[N] = E;
}
__global__ __launch_bounds__(256) void scan_block(const int* __restrict__ cnt,
                                                  const int* __restrict__ boff,
                                                  int* __restrict__ offs,
                                                  int* __restrict__ cursor, int N) {
  __shared__ int sd[256];
  int t = threadIdx.x;
  int i = blockIdx.x * 256 + t;
  int v = (i < N) ? cnt[i] : 0;
  sd[t] = v;
  __syncthreads();
  for (int d = 1; d < 256; d <<= 1) {
    int x = sd[t];
    if (t >= d) x += sd[t - d];
    __syncthreads();
    sd[t] = x;
    __syncthreads();
  }
  if (i < N) {
    int o = boff[blockIdx.x] + sd[t] - v;
    offs[i] = o;
    cursor[i] = o;
  }
}
__global__ __launch_bounds__(256) void scatter_edges(const int* __restrict__ src,
                                                     const int* __restrict__ dst,
                                                     int* __restrict__ cursor,
                                                     int* __restrict__ esrc, int E) {
  int i = blockIdx.x * 256 + threadIdx.x;
  if (i < E) {
    int pos = atomicAdd(&cursor[dst[i]], 1);
    esrc[pos] = src[i];
  }
}

// ---------- A-fragment: 8 consecutive f32 -> bf16, per MFMA 16x16x32 layout ----------
__device__ __forceinline__ short8 load_afrag(const float* __restrict__ base, int row, int ko) {
  const float* p = base + (size_t)row * DH + ko;
  float4 a = *(const float4*)p;
  float4 b = *(const float4*)(p + 4);
  union { short8 v; unsigned short s[8]; } u;
  u.s[0] = f2bf(a.x); u.s[1] = f2bf(a.y); u.s[2] = f2bf(a.z); u.s[3] = f2bf(a.w);
  u.s[4] = f2bf(b.x); u.s[5] = f2bf(b.y); u.s[6] = f2bf(b.z); u.s[7] = f2bf(b.w);
  return u.v;
}

// ---------- K1: m = sigmoid(f_dst@wr + h@ur + br) * h   (m stored bf16) ----------
__global__ __launch_bounds__(256) void k1_node_gate(
    const float* __restrict__ fdst, const float* __restrict__ h,
    const unsigned short* __restrict__ wf, const float* __restrict__ br,
    unsigned short* __restrict__ m, int N) {
  const unsigned short* wrf = wf + 2 * 16384;
  const unsigned short* urf = wf + 3 * 16384;
  int lane = threadIdx.x & 63, wid = threadIdx.x >> 6;
  int rowb = blockIdx.x * 64 + wid * 16;
  int mrow = lane & 15, g = lane >> 4;
  int arow = rowb + mrow; if (arow > N - 1) arow = N - 1;
  f32x4 acc[8];
#pragma unroll
  for (int i = 0; i < 8; ++i) acc[i] = (f32x4){0.f, 0.f, 0.f, 0.f};
#pragma unroll
  for (int kh = 0; kh < 2; ++kh) {
    const float* srcm = kh ? h : fdst;
    const unsigned short* bfm = kh ? urf : wrf;
#pragma unroll
    for (int kt = 0; kt < 4; ++kt) {
      short8 af = load_afrag(srcm, arow, kt * 32 + g * 8);
#pragma unroll
      for (int nt = 0; nt < 8; ++nt) {
        short8 bf = *(const short8*)&bfm[(kt * 8 + nt) * 512 + lane * 8];
        acc[nt] = __builtin_amdgcn_mfma_f32_16x16x32_bf16(af, bf, acc[nt], 0, 0, 0);
      }
    }
  }
  int orow = rowb + g * 4;
#pragma unroll
  for (int nt = 0; nt < 8; ++nt) {
    int col = nt * 16 + mrow;
    float bias = br[col];
#pragma unroll
    for (int r = 0; r < 4; ++r) {
      int row = orow + r;
      if (row < N) {
        float arg = acc[nt][r] + bias;
        float gv = 1.f / (1.f + __expf(-arg));
        float mv = gv * h[(size_t)row * DH + col];
        m[(size_t)row * DH + col] = f2bf(mv);
      }
    }
  }
}

// ---------- K3: per-node gather-sum: s[v] = sum h[src], mrh[v] = sum m[src] ----------
__global__ __launch_bounds__(256) void k3_gather(
    const int* __restrict__ offs, const int* __restrict__ esrc,
    const float* __restrict__ h, const unsigned short* __restrict__ m,
    float* __restrict__ s, float* __restrict__ mrh, int N) {
  int lane = threadIdx.x & 63, wid = threadIdx.x >> 6;
  int v = blockIdx.x * 4 + wid;
  if (v >= N) return;
  int e0 = offs[v], e1 = offs[v + 1];
  float sx = 0.f, sy = 0.f, mx = 0.f, my = 0.f;
  size_t c = (size_t)lane * 2;
  int e = e0;
  for (; e + 1 < e1; e += 2) {
    int u0 = esrc[e], u1 = esrc[e + 1];
    float2 h0 = *(const float2*)&h[(size_t)u0 * DH + c];
    float2 h1 = *(const float2*)&h[(size_t)u1 * DH + c];
    uint32_t m0 = *(const uint32_t*)&m[(size_t)u0 * DH + c];
    uint32_t m1 = *(const uint32_t*)&m[(size_t)u1 * DH + c];
    sx += h0.x + h1.x;
    sy += h0.y + h1.y;
    mx += bf2f((unsigned short)(m0 & 0xffff)) + bf2f((unsigned short)(m1 & 0xffff));
    my += bf2f((unsigned short)(m0 >> 16)) + bf2f((unsigned short)(m1 >> 16));
  }
  if (e < e1) {
    int u0 = esrc[e];
    float2 h0 = *(const float2*)&h[(size_t)u0 * DH + c];
    uint32_t m0 = *(const uint32_t*)&m[(size_t)u0 * DH + c];
    sx += h0.x; sy += h0.y;
    mx += bf2f((unsigned short)(m0 & 0xffff));
    my += bf2f((unsigned short)(m0 >> 16));
  }
  float2 so; so.x = sx; so.y = sy;
  float2 mo; mo.x = mx; mo.y = my;
  *(float2*)&s[(size_t)v * DH + c] = so;
  *(float2*)&mrh[(size_t)v * DH + c] = mo;
}

// ---------- K4: z/h_tilde GEMMs + gated update; reads s from d_out, overwrites with h_new
__global__ __launch_bounds__(256) void k4_update(
    const float* __restrict__ fsrc, const float* __restrict__ s,
    const float* __restrict__ mrh, const unsigned short* __restrict__ wf,
    const float* __restrict__ bz, const float* __restrict__ bb,
    float* __restrict__ out, int N) {
  const unsigned short* wzf = wf + 0 * 16384;
  const unsigned short* uzf = wf + 1 * 16384;
  const unsigned short* wwf = wf + 4 * 16384;
  const unsigned short* uuf = wf + 5 * 16384;
  int lane = threadIdx.x & 63, wid = threadIdx.x >> 6;
  int rowb = blockIdx.x * 64 + wid * 16;
  int mrow = lane & 15, g = lane >> 4;
  int arow = rowb + mrow; if (arow > N - 1) arow = N - 1;
  f32x4 az[8], ah[8];
#pragma unroll
  for (int i = 0; i < 8; ++i) {
    az[i] = (f32x4){0.f, 0.f, 0.f, 0.f};
    ah[i] = (f32x4){0.f, 0.f, 0.f, 0.f};
  }
  // phase 1: f_src contributes to both gates
#pragma unroll
  for (int kt = 0; kt < 4; ++kt) {
    short8 af = load_afrag(fsrc, arow, kt * 32 + g * 8);
#pragma unroll
    for (int nt = 0; nt < 8; ++nt) {
      short8 b0 = *(const short8*)&wzf[(kt * 8 + nt) * 512 + lane * 8];
      short8 b1 = *(const short8*)&wwf[(kt * 8 + nt) * 512 + lane * 8];
      az[nt] = __builtin_amdgcn_mfma_f32_16x16x32_bf16(af, b0, az[nt], 0, 0, 0);
      ah[nt] = __builtin_amdgcn_mfma_f32_16x16x32_bf16(af, b1, ah[nt], 0, 0, 0);
    }
  }
  // phase 2: s @ uz -> z gate
#pragma unroll
  for (int kt = 0; kt < 4; ++kt) {
    short8 af = load_afrag(s, arow, kt * 32 + g * 8);
#pragma unroll
    for (int nt = 0; nt < 8; ++nt) {
      short8 b0 = *(const short8*)&uzf[(kt * 8 + nt) * 512 + lane * 8];
      az[nt] = __builtin_amdgcn_mfma_f32_16x16x32_bf16(af, b0, az[nt], 0, 0, 0);
    }
  }
  // phase 3: mrh @ u -> candidate
#pragma unroll
  for (int kt = 0; kt < 4; ++kt) {
    short8 af = load_afrag(mrh, arow, kt * 32 + g * 8);
#pragma unroll
    for (int nt = 0; nt < 8; ++nt) {
      short8 b1 = *(const short8*)&uuf[(kt * 8 + nt) * 512 + lane * 8];
      ah[nt] = __builtin_amdgcn_mfma_f32_16x16x32_bf16(af, b1, ah[nt], 0, 0, 0);
    }
  }
  int orow = rowb + g * 4;
#pragma unroll
  for (int nt = 0; nt < 8; ++nt) {
    int col = nt * 16 + mrow;
    float bzc = bz[col], bbc = bb[col];
#pragma unroll
    for (int r = 0; r < 4; ++r) {
      int row = orow + r;
      if (row < N) {
        float zarg = az[nt][r] + bzc;
        float z = 1.f / (1.f + __expf(-zarg));
        float e2 = __expf(2.f * (ah[nt][r] + bbc));
        float th = (e2 - 1.f) / (e2 + 1.f);
        float sv = s[(size_t)row * DH + col];
        out[(size_t)row * DH + col] = (1.f - z) * sv + z * th;
      }
    }
  }
}

extern "C" void kernel_launch(void* const* d_in, const int* in_sizes, int n_in,
                              void* d_out, int out_size, void* d_ws, size_t ws_size,
                              hipStream_t stream) {
  const float* h    = (const float*)d_in[0];
  const float* fsrc = (const float*)d_in[1];
  const float* fdst = (const float*)d_in[2];
  const int*   src  = (const int*)d_in[3];
  const int*   dst  = (const int*)d_in[4];
  const float* wz   = (const float*)d_in[5];
  const float* uz   = (const float*)d_in[6];
  const float* bz   = (const float*)d_in[7];
  const float* wr   = (const float*)d_in[8];
  const float* ur   = (const float*)d_in[9];
  const float* br   = (const float*)d_in[10];
  const float* w    = (const float*)d_in[11];
  const float* u    = (const float*)d_in[12];
  const float* b    = (const float*)d_in[13];
  int N = in_sizes[0] / DH;
  int E = in_sizes[3];
  float* out = (float*)d_out;

  char* ws = (char*)d_ws;
  size_t o = 0;
  auto take = [&](size_t bytes) {
    char* p = ws + o;
    o = (o + bytes + 255) & ~(size_t)255;
    return p;
  };
  unsigned short* wf     = (unsigned short*)take(6 * 16384 * sizeof(unsigned short));
  unsigned short* mbuf   = (unsigned short*)take((size_t)N * DH * 2);
  float*          mrh    = (float*)take((size_t)N * DH * 4);
  int*            cnt    = (int*)take((size_t)N * 4);
  int*            offs   = (int*)take((size_t)(N + 1) * 4);
  int*            cursor = (int*)take((size_t)N * 4);
  int*            bsum   = (int*)take(4096);
  int*            esrc   = (int*)take((size_t)E * 4);

  int nb = (N + 255) / 256;  // 391 for N=100000; scan_bsums assumes nb <= 512

  pack_weights<<<(6 * 16384 + 255) / 256, 256, 0, stream>>>(wz, uz, wr, ur, w, u, wf);
  zero_counts<<<nb, 256, 0, stream>>>(cnt, N);
  count_deg<<<(E + 255) / 256, 256, 0, stream>>>(dst, cnt, E);
  block_reduce<<<nb, 256, 0, stream>>>(cnt, bsum, N);
  scan_bsums<<<1, 512, 0, stream>>>(bsum, nb, offs, N, E);
  scan_block<<<nb, 256, 0, stream>>>(cnt, bsum, offs, cursor, N);
  scatter_edges<<<(E + 255) / 256, 256, 0, stream>>>(src, dst, cursor, esrc, E);
  k1_node_gate<<<(N + 63) / 64, 256, 0, stream>>>(fdst, h, wf, br, mbuf, N);
  k3_gather<<<(N + 3) / 4, 256, 0, stream>>>(offs, esrc, h, mbuf, out, mrh, N);
  k4_update<<<(N + 63) / 64, 256, 0, stream>>>(fsrc, out, mrh, wf, bz, b, out, N);
}

// Round 2
// 673.733 us; speedup vs baseline: 1.0120x; 1.0120x over previous
//
#include <hip/hip_runtime.h>
#include <stdint.h>

#define DH 128

typedef __attribute__((ext_vector_type(8))) short short8;
typedef __attribute__((ext_vector_type(4))) float f32x4;

__device__ __forceinline__ unsigned short f2bf(float f) {
  union { float f; unsigned u; } v; v.f = f;
  unsigned r = v.u + 0x7fffu + ((v.u >> 16) & 1u);
  return (unsigned short)(r >> 16);
}
__device__ __forceinline__ uint32_t cvtpk_bf16(float lo, float hi) {
  uint32_t r;
  asm("v_cvt_pk_bf16_f32 %0, %1, %2" : "=v"(r) : "v"(lo), "v"(hi));
  return r;
}
__device__ __forceinline__ float bflo(uint32_t u) {
  union { uint32_t u; float f; } v; v.u = u << 16; return v.f;
}
__device__ __forceinline__ float bfhi(uint32_t u) {
  union { uint32_t u; float f; } v; v.u = u & 0xffff0000u; return v.f;
}

// ---------- K0: pack 6 weight matrices [128x128] f32 -> bf16 MFMA B-frag layout
// layout index: ((mat*4 + kt)*8 + nt)*64*8 + lane*8 + j
// frag element j of lane: B[k = kt*32 + (lane>>4)*8 + j][n = nt*16 + (lane&15)]
__global__ __launch_bounds__(256) void pack_weights(
    const float* __restrict__ wz, const float* __restrict__ uz,
    const float* __restrict__ wr, const float* __restrict__ ur,
    const float* __restrict__ w,  const float* __restrict__ u,
    unsigned short* __restrict__ wf) {
  int t = blockIdx.x * 256 + threadIdx.x;
  if (t >= 6 * 16384) return;
  int mat = t >> 14;
  int r = t & 16383;
  int j = r & 7;
  int lane = (r >> 3) & 63;
  int nt = (r >> 9) & 7;
  int kt = (r >> 12) & 3;
  int k = kt * 32 + ((lane >> 4) << 3) + j;
  int n = nt * 16 + (lane & 15);
  const float* m_;
  switch (mat) {
    case 0: m_ = wz; break; case 1: m_ = uz; break; case 2: m_ = wr; break;
    case 3: m_ = ur; break; case 4: m_ = w;  break; default: m_ = u;
  }
  wf[t] = f2bf(m_[k * DH + n]);
}

// ---------- K2 chain: CSR build by dst ----------
__global__ __launch_bounds__(256) void zero_counts(int* __restrict__ cnt, int N) {
  int i = blockIdx.x * 256 + threadIdx.x;
  if (i < N) cnt[i] = 0;
}
__global__ __launch_bounds__(256) void count_deg(const int* __restrict__ dst,
                                                 int* __restrict__ cnt, int E) {
  int i = blockIdx.x * 256 + threadIdx.x;
  if (i < E) atomicAdd(&cnt[dst[i]], 1);
}
__global__ __launch_bounds__(256) void block_reduce(const int* __restrict__ cnt,
                                                    int* __restrict__ bsum, int N) {
  __shared__ int sd[256];
  int t = threadIdx.x;
  int i = blockIdx.x * 256 + t;
  sd[t] = (i < N) ? cnt[i] : 0;
  __syncthreads();
  for (int d = 128; d > 0; d >>= 1) {
    if (t < d) sd[t] += sd[t + d];
    __syncthreads();
  }
  if (t == 0) bsum[blockIdx.x] = sd[0];
}
// single block: exclusive-scan bsum[0..nb) in place (nb <= 512), write offs[N]=E
__global__ __launch_bounds__(512) void scan_bsums(int* __restrict__ bsum, int nb,
                                                  int* __restrict__ offs, int N, int E) {
  __shared__ int sd[512];
  int t = threadIdx.x;
  int v = (t < nb) ? bsum[t] : 0;
  sd[t] = v;
  __syncthreads();
  for (int d = 1; d < 512; d <<= 1) {
    int x = sd[t];
    if (t >= d) x += sd[t - d];
    __syncthreads();
    sd[t] = x;
    __syncthreads();
  }
  if (t < nb) bsum[t] = sd[t] - v;  // exclusive
  if (t == 0) offs[N] = E;
}
__global__ __launch_bounds__(256) void scan_block(const int* __restrict__ cnt,
                                                  const int* __restrict__ boff,
                                                  int* __restrict__ offs,
                                                  int* __restrict__ cursor, int N) {
  __shared__ int sd[256];
  int t = threadIdx.x;
  int i = blockIdx.x * 256 + t;
  int v = (i < N) ? cnt[i] : 0;
  sd[t] = v;
  __syncthreads();
  for (int d = 1; d < 256; d <<= 1) {
    int x = sd[t];
    if (t >= d) x += sd[t - d];
    __syncthreads();
    sd[t] = x;
    __syncthreads();
  }
  if (i < N) {
    int o = boff[blockIdx.x] + sd[t] - v;
    offs[i] = o;
    cursor[i] = o;
  }
}
__global__ __launch_bounds__(256) void scatter_edges(const int* __restrict__ src,
                                                     const int* __restrict__ dst,
                                                     int* __restrict__ cursor,
                                                     int* __restrict__ esrc, int E) {
  int i = blockIdx.x * 256 + threadIdx.x;
  if (i < E) {
    int pos = atomicAdd(&cursor[dst[i]], 1);
    esrc[pos] = src[i];
  }
}

// ---------- A-fragment loaders ----------
__device__ __forceinline__ short8 load_afrag(const float* __restrict__ base, int row, int ko) {
  const float* p = base + (size_t)row * DH + ko;
  float4 a = *(const float4*)p;
  float4 b = *(const float4*)(p + 4);
  union { short8 v; uint32_t u[4]; } r;
  r.u[0] = cvtpk_bf16(a.x, a.y);
  r.u[1] = cvtpk_bf16(a.z, a.w);
  r.u[2] = cvtpk_bf16(b.x, b.y);
  r.u[3] = cvtpk_bf16(b.z, b.w);
  return r.v;
}
__device__ __forceinline__ short8 load_afrag_bf(const unsigned short* __restrict__ base,
                                                int row, int ko) {
  return *(const short8*)(base + (size_t)row * DH + ko);
}

// ---------- K1: m = sigmoid(f_dst@wr + h@ur + br) * h   (m stored bf16) ----------
__global__ __launch_bounds__(256) void k1_node_gate(
    const float* __restrict__ fdst, const float* __restrict__ h,
    const unsigned short* __restrict__ wf, const float* __restrict__ br,
    unsigned short* __restrict__ m, int N) {
  const unsigned short* wrf = wf + 2 * 16384;
  const unsigned short* urf = wf + 3 * 16384;
  int lane = threadIdx.x & 63, wid = threadIdx.x >> 6;
  int rowb = blockIdx.x * 64 + wid * 16;
  int mrow = lane & 15, g = lane >> 4;
  int arow = rowb + mrow; if (arow > N - 1) arow = N - 1;
  f32x4 acc[8];
#pragma unroll
  for (int i = 0; i < 8; ++i) acc[i] = (f32x4){0.f, 0.f, 0.f, 0.f};
#pragma unroll
  for (int kh = 0; kh < 2; ++kh) {
    const float* srcm = kh ? h : fdst;
    const unsigned short* bfm = kh ? urf : wrf;
#pragma unroll
    for (int kt = 0; kt < 4; ++kt) {
      short8 af = load_afrag(srcm, arow, kt * 32 + g * 8);
#pragma unroll
      for (int nt = 0; nt < 8; ++nt) {
        short8 bf = *(const short8*)&bfm[(kt * 8 + nt) * 512 + lane * 8];
        acc[nt] = __builtin_amdgcn_mfma_f32_16x16x32_bf16(af, bf, acc[nt], 0, 0, 0);
      }
    }
  }
  int orow = rowb + g * 4;
#pragma unroll
  for (int nt = 0; nt < 8; ++nt) {
    int col = nt * 16 + mrow;
    float bias = br[col];
#pragma unroll
    for (int r = 0; r < 4; ++r) {
      int row = orow + r;
      if (row < N) {
        float arg = acc[nt][r] + bias;
        float gv = 1.f / (1.f + __expf(-arg));
        float mv = gv * h[(size_t)row * DH + col];
        m[(size_t)row * DH + col] = f2bf(mv);
      }
    }
  }
}

// ---------- K3: per-node gather-sum: s[v] = sum h[src] (f32), mrh[v] = sum m[src] (bf16 out)
__global__ __launch_bounds__(256) void k3_gather(
    const int* __restrict__ offs, const int* __restrict__ esrc,
    const float* __restrict__ h, const unsigned short* __restrict__ m,
    float* __restrict__ s, unsigned short* __restrict__ mrh, int N) {
  int lane = threadIdx.x & 63, wid = threadIdx.x >> 6;
  int v = blockIdx.x * 4 + wid;
  if (v >= N) return;
  int e0 = offs[v], e1 = offs[v + 1];
  float sx = 0.f, sy = 0.f, mx = 0.f, my = 0.f;
  size_t c = (size_t)(lane * 2);
  int e = e0;
  // unroll 4: 8 independent row loads in flight -> MLP, not latency-serial
  for (; e + 3 < e1; e += 4) {
    int u0 = esrc[e], u1 = esrc[e + 1], u2 = esrc[e + 2], u3 = esrc[e + 3];
    float2 h0 = *(const float2*)&h[(size_t)u0 * DH + c];
    float2 h1 = *(const float2*)&h[(size_t)u1 * DH + c];
    float2 h2 = *(const float2*)&h[(size_t)u2 * DH + c];
    float2 h3 = *(const float2*)&h[(size_t)u3 * DH + c];
    uint32_t m0 = *(const uint32_t*)&m[(size_t)u0 * DH + c];
    uint32_t m1 = *(const uint32_t*)&m[(size_t)u1 * DH + c];
    uint32_t m2 = *(const uint32_t*)&m[(size_t)u2 * DH + c];
    uint32_t m3 = *(const uint32_t*)&m[(size_t)u3 * DH + c];
    sx += (h0.x + h1.x) + (h2.x + h3.x);
    sy += (h0.y + h1.y) + (h2.y + h3.y);
    mx += (bflo(m0) + bflo(m1)) + (bflo(m2) + bflo(m3));
    my += (bfhi(m0) + bfhi(m1)) + (bfhi(m2) + bfhi(m3));
  }
  for (; e < e1; ++e) {
    int u0 = esrc[e];
    float2 h0 = *(const float2*)&h[(size_t)u0 * DH + c];
    uint32_t m0 = *(const uint32_t*)&m[(size_t)u0 * DH + c];
    sx += h0.x; sy += h0.y;
    mx += bflo(m0); my += bfhi(m0);
  }
  float2 so; so.x = sx; so.y = sy;
  *(float2*)&s[(size_t)v * DH + c] = so;
  *(uint32_t*)&mrh[(size_t)v * DH + c] = cvtpk_bf16(mx, my);
}

// ---------- K4: z/h_tilde GEMMs + gated update; reads s from d_out, overwrites with h_new
__global__ __launch_bounds__(256) void k4_update(
    const float* __restrict__ fsrc, const float* __restrict__ s,
    const unsigned short* __restrict__ mrh, const unsigned short* __restrict__ wf,
    const float* __restrict__ bz, const float* __restrict__ bb,
    float* __restrict__ out, int N) {
  const unsigned short* wzf = wf + 0 * 16384;
  const unsigned short* uzf = wf + 1 * 16384;
  const unsigned short* wwf = wf + 4 * 16384;
  const unsigned short* uuf = wf + 5 * 16384;
  int lane = threadIdx.x & 63, wid = threadIdx.x >> 6;
  int rowb = blockIdx.x * 64 + wid * 16;
  int mrow = lane & 15, g = lane >> 4;
  int arow = rowb + mrow; if (arow > N - 1) arow = N - 1;
  f32x4 az[8], ah[8];
#pragma unroll
  for (int i = 0; i < 8; ++i) {
    az[i] = (f32x4){0.f, 0.f, 0.f, 0.f};
    ah[i] = (f32x4){0.f, 0.f, 0.f, 0.f};
  }
  // phase 1: f_src contributes to both gates
#pragma unroll
  for (int kt = 0; kt < 4; ++kt) {
    short8 af = load_afrag(fsrc, arow, kt * 32 + g * 8);
#pragma unroll
    for (int nt = 0; nt < 8; ++nt) {
      short8 b0 = *(const short8*)&wzf[(kt * 8 + nt) * 512 + lane * 8];
      short8 b1 = *(const short8*)&wwf[(kt * 8 + nt) * 512 + lane * 8];
      az[nt] = __builtin_amdgcn_mfma_f32_16x16x32_bf16(af, b0, az[nt], 0, 0, 0);
      ah[nt] = __builtin_amdgcn_mfma_f32_16x16x32_bf16(af, b1, ah[nt], 0, 0, 0);
    }
  }
  // phase 2: s @ uz -> z gate
#pragma unroll
  for (int kt = 0; kt < 4; ++kt) {
    short8 af = load_afrag(s, arow, kt * 32 + g * 8);
#pragma unroll
    for (int nt = 0; nt < 8; ++nt) {
      short8 b0 = *(const short8*)&uzf[(kt * 8 + nt) * 512 + lane * 8];
      az[nt] = __builtin_amdgcn_mfma_f32_16x16x32_bf16(af, b0, az[nt], 0, 0, 0);
    }
  }
  // phase 3: mrh @ u -> candidate (mrh is bf16, direct frag load)
#pragma unroll
  for (int kt = 0; kt < 4; ++kt) {
    short8 af = load_afrag_bf(mrh, arow, kt * 32 + g * 8);
#pragma unroll
    for (int nt = 0; nt < 8; ++nt) {
      short8 b1 = *(const short8*)&uuf[(kt * 8 + nt) * 512 + lane * 8];
      ah[nt] = __builtin_amdgcn_mfma_f32_16x16x32_bf16(af, b1, ah[nt], 0, 0, 0);
    }
  }
  int orow = rowb + g * 4;
#pragma unroll
  for (int nt = 0; nt < 8; ++nt) {
    int col = nt * 16 + mrow;
    float bzc = bz[col], bbc = bb[col];
#pragma unroll
    for (int r = 0; r < 4; ++r) {
      int row = orow + r;
      if (row < N) {
        float zarg = az[nt][r] + bzc;
        float z = 1.f / (1.f + __expf(-zarg));
        float e2 = __expf(2.f * (ah[nt][r] + bbc));
        float th = (e2 - 1.f) / (e2 + 1.f);
        float sv = s[(size_t)row * DH + col];
        out[(size_t)row * DH + col] = (1.f - z) * sv + z * th;
      }
    }
  }
}

extern "C" void kernel_launch(void* const* d_in, const int* in_sizes, int n_in,
                              void* d_out, int out_size, void* d_ws, size_t ws_size,
                              hipStream_t stream) {
  const float* h    = (const float*)d_in[0];
  const float* fsrc = (const float*)d_in[1];
  const float* fdst = (const float*)d_in[2];
  const int*   src  = (const int*)d_in[3];
  const int*   dst  = (const int*)d_in[4];
  const float* wz   = (const float*)d_in[5];
  const float* uz   = (const float*)d_in[6];
  const float* bz   = (const float*)d_in[7];
  const float* wr   = (const float*)d_in[8];
  const float* ur   = (const float*)d_in[9];
  const float* br   = (const float*)d_in[10];
  const float* w    = (const float*)d_in[11];
  const float* u    = (const float*)d_in[12];
  const float* b    = (const float*)d_in[13];
  int N = in_sizes[0] / DH;
  int E = in_sizes[3];
  float* out = (float*)d_out;

  char* ws = (char*)d_ws;
  size_t o = 0;
  auto take = [&](size_t bytes) {
    char* p = ws + o;
    o = (o + bytes + 255) & ~(size_t)255;
    return p;
  };
  unsigned short* wf     = (unsigned short*)take(6 * 16384 * sizeof(unsigned short));
  unsigned short* mbuf   = (unsigned short*)take((size_t)N * DH * 2);
  unsigned short* mrh    = (unsigned short*)take((size_t)N * DH * 2);
  int*            cnt    = (int*)take((size_t)N * 4);
  int*            offs   = (int*)take((size_t)(N + 1) * 4);
  int*            cursor = (int*)take((size_t)N * 4);
  int*            bsum   = (int*)take(4096);
  int*            esrc   = (int*)take((size_t)E * 4);

  int nb = (N + 255) / 256;  // 391 for N=100000; scan_bsums assumes nb <= 512

  pack_weights<<<(6 * 16384 + 255) / 256, 256, 0, stream>>>(wz, uz, wr, ur, w, u, wf);
  zero_counts<<<nb, 256, 0, stream>>>(cnt, N);
  count_deg<<<(E + 255) / 256, 256, 0, stream>>>(dst, cnt, E);
  block_reduce<<<nb, 256, 0, stream>>>(cnt, bsum, N);
  scan_bsums<<<1, 512, 0, stream>>>(bsum, nb, offs, N, E);
  scan_block<<<nb, 256, 0, stream>>>(cnt, bsum, offs, cursor, N);
  scatter_edges<<<(E + 255) / 256, 256, 0, stream>>>(src, dst, cursor, esrc, E);
  k1_node_gate<<<(N + 63) / 64, 256, 0, stream>>>(fdst, h, wf, br, mbuf, N);
  k3_gather<<<(N + 3) / 4, 256, 0, stream>>>(offs, esrc, h, mbuf, out, mrh, N);
  k4_update<<<(N + 63) / 64, 256, 0, stream>>>(fsrc, out, mrh, wf, bz, b, out, N);
}

// Round 4
// 629.487 us; speedup vs baseline: 1.0831x; 1.0703x over previous
//
#include <hip/hip_runtime.h>
#include <stdint.h>

#define DH 128

typedef __attribute__((ext_vector_type(8))) _Float16 half8;
typedef __attribute__((ext_vector_type(2))) _Float16 half2v;
typedef __attribute__((ext_vector_type(2))) __fp16 fp16x2;
typedef __attribute__((ext_vector_type(4))) float f32x4;

// ---------- K0: pack 6 weight matrices [128x128] f32 -> f16 MFMA B-frag layout
// layout index: ((mat*4 + kt)*8 + nt)*64*8 + lane*8 + j
// frag element j of lane: B[k = kt*32 + (lane>>4)*8 + j][n = nt*16 + (lane&15)]
__global__ __launch_bounds__(256) void pack_weights(
    const float* __restrict__ wz, const float* __restrict__ uz,
    const float* __restrict__ wr, const float* __restrict__ ur,
    const float* __restrict__ w,  const float* __restrict__ u,
    _Float16* __restrict__ wf) {
  int t = blockIdx.x * 256 + threadIdx.x;
  if (t >= 6 * 16384) return;
  int mat = t >> 14;
  int r = t & 16383;
  int j = r & 7;
  int lane = (r >> 3) & 63;
  int nt = (r >> 9) & 7;
  int kt = (r >> 12) & 3;
  int k = kt * 32 + ((lane >> 4) << 3) + j;
  int n = nt * 16 + (lane & 15);
  const float* m_;
  switch (mat) {
    case 0: m_ = wz; break; case 1: m_ = uz; break; case 2: m_ = wr; break;
    case 3: m_ = ur; break; case 4: m_ = w;  break; default: m_ = u;
  }
  wf[t] = (_Float16)m_[k * DH + n];
}

// ---------- K2 chain: CSR build by dst ----------
__global__ __launch_bounds__(256) void count_deg(const int* __restrict__ dst,
                                                 int* __restrict__ cnt, int E) {
  int i = (blockIdx.x * 256 + threadIdx.x) * 4;
  if (i + 3 < E) {
    int4 d = *(const int4*)&dst[i];
    atomicAdd(&cnt[d.x], 1);
    atomicAdd(&cnt[d.y], 1);
    atomicAdd(&cnt[d.z], 1);
    atomicAdd(&cnt[d.w], 1);
  } else {
    for (; i < E; ++i) atomicAdd(&cnt[dst[i]], 1);
  }
}
__global__ __launch_bounds__(256) void block_reduce(const int* __restrict__ cnt,
                                                    int* __restrict__ bsum, int N) {
  __shared__ int sd[256];
  int t = threadIdx.x;
  int i = blockIdx.x * 256 + t;
  sd[t] = (i < N) ? cnt[i] : 0;
  __syncthreads();
  for (int d = 128; d > 0; d >>= 1) {
    if (t < d) sd[t] += sd[t + d];
    __syncthreads();
  }
  if (t == 0) bsum[blockIdx.x] = sd[0];
}
// single block: exclusive-scan bsum[0..nb) in place (nb <= 512), write offs[N]=E
__global__ __launch_bounds__(512) void scan_bsums(int* __restrict__ bsum, int nb,
                                                  int* __restrict__ offs, int N, int E) {
  __shared__ int sd[512];
  int t = threadIdx.x;
  int v = (t < nb) ? bsum[t] : 0;
  sd[t] = v;
  __syncthreads();
  for (int d = 1; d < 512; d <<= 1) {
    int x = sd[t];
    if (t >= d) x += sd[t - d];
    __syncthreads();
    sd[t] = x;
    __syncthreads();
  }
  if (t < nb) bsum[t] = sd[t] - v;  // exclusive
  if (t == 0) offs[N] = E;
}
__global__ __launch_bounds__(256) void scan_block(const int* __restrict__ cnt,
                                                  const int* __restrict__ boff,
                                                  int* __restrict__ offs,
                                                  int* __restrict__ cursor, int N) {
  __shared__ int sd[256];
  int t = threadIdx.x;
  int i = blockIdx.x * 256 + t;
  int v = (i < N) ? cnt[i] : 0;
  sd[t] = v;
  __syncthreads();
  for (int d = 1; d < 256; d <<= 1) {
    int x = sd[t];
    if (t >= d) x += sd[t - d];
    __syncthreads();
    sd[t] = x;
    __syncthreads();
  }
  if (i < N) {
    int o = boff[blockIdx.x] + sd[t] - v;
    offs[i] = o;
    cursor[i] = o;
  }
}
__global__ __launch_bounds__(256) void scatter_edges(const int* __restrict__ src,
                                                     const int* __restrict__ dst,
                                                     int* __restrict__ cursor,
                                                     int* __restrict__ esrc, int E) {
  int i = blockIdx.x * 256 + threadIdx.x;
  if (i < E) {
    int pos = atomicAdd(&cursor[dst[i]], 1);
    esrc[pos] = src[i];
  }
}

// ---------- A-fragment loaders (f32 -> f16 packed convert) ----------
__device__ __forceinline__ half8 load_afrag(const float* __restrict__ base, int row, int ko) {
  const float* p = base + (size_t)row * DH + ko;
  float4 a = *(const float4*)p;
  float4 b = *(const float4*)(p + 4);
  union { half8 v; fp16x2 h[4]; } r;
  r.h[0] = __builtin_amdgcn_cvt_pkrtz(a.x, a.y);
  r.h[1] = __builtin_amdgcn_cvt_pkrtz(a.z, a.w);
  r.h[2] = __builtin_amdgcn_cvt_pkrtz(b.x, b.y);
  r.h[3] = __builtin_amdgcn_cvt_pkrtz(b.z, b.w);
  return r.v;
}
__device__ __forceinline__ half8 load_afrag_h(const _Float16* __restrict__ base,
                                              int row, int ko) {
  return *(const half8*)(base + (size_t)row * DH + ko);
}

// ---------- K1: m = sigmoid(f_dst@wr + h@ur + br) * h ----------
// Writes interleaved fp16 row hm[node]: 256 halves, pair p: [h_{2p}, h_{2p+1}, m_{2p}, m_{2p+1}]
__global__ __launch_bounds__(256) void k1_node_gate(
    const float* __restrict__ fdst, const float* __restrict__ h,
    const _Float16* __restrict__ wf, const float* __restrict__ br,
    _Float16* __restrict__ hm, int N) {
  const _Float16* wrf = wf + 2 * 16384;
  const _Float16* urf = wf + 3 * 16384;
  int lane = threadIdx.x & 63, wid = threadIdx.x >> 6;
  int rowb = blockIdx.x * 64 + wid * 16;
  int mrow = lane & 15, g = lane >> 4;
  int arow = rowb + mrow; if (arow > N - 1) arow = N - 1;
  f32x4 acc[8];
#pragma unroll
  for (int i = 0; i < 8; ++i) acc[i] = (f32x4){0.f, 0.f, 0.f, 0.f};
#pragma unroll
  for (int kh = 0; kh < 2; ++kh) {
    const float* srcm = kh ? h : fdst;
    const _Float16* bfm = kh ? urf : wrf;
#pragma unroll
    for (int kt = 0; kt < 4; ++kt) {
      half8 af = load_afrag(srcm, arow, kt * 32 + g * 8);
#pragma unroll
      for (int nt = 0; nt < 8; ++nt) {
        half8 bf = *(const half8*)&bfm[(kt * 8 + nt) * 512 + lane * 8];
        acc[nt] = __builtin_amdgcn_mfma_f32_16x16x32_f16(af, bf, acc[nt], 0, 0, 0);
      }
    }
  }
  int orow = rowb + g * 4;
#pragma unroll
  for (int nt = 0; nt < 8; ++nt) {
    int col = nt * 16 + mrow;
    float bias = br[col];
#pragma unroll
    for (int r = 0; r < 4; ++r) {
      int row = orow + r;
      if (row < N) {
        float hval = h[(size_t)row * DH + col];
        float arg = acc[nt][r] + bias;
        float gv = 1.f / (1.f + __expf(-arg));
        float mv = gv * hval;
        size_t base = (size_t)row * 256 + (size_t)((col >> 1) << 2) + (col & 1);
        hm[base] = (_Float16)hval;
        hm[base + 2] = (_Float16)mv;
      }
    }
  }
}

// ---------- K3: per-node gather-sum over interleaved fp16 rows ----------
// s[v] = sum h[src] (f32 accum), mrh[v] = sum m[src] (fp16 packed accum)
__global__ __launch_bounds__(256) void k3_gather(
    const int* __restrict__ offs, const int* __restrict__ esrc,
    const _Float16* __restrict__ hm,
    float* __restrict__ s, _Float16* __restrict__ mrh, int N) {
  int lane = threadIdx.x & 63, wid = threadIdx.x >> 6;
  int v = blockIdx.x * 4 + wid;
  if (v >= N) return;
  int e0 = offs[v], e1 = offs[v + 1];
  float sx = 0.f, sy = 0.f;
  half2v msum = (half2v)(_Float16)0.f;
  int c4 = lane * 4;  // half-offset within 256-half row; byte offset = lane*8
  int e = e0;
  for (; e + 3 < e1; e += 4) {
    int4 uu = *(const int4*)&esrc[e];
    uint2 q0 = *(const uint2*)(hm + (size_t)uu.x * 256 + c4);
    uint2 q1 = *(const uint2*)(hm + (size_t)uu.y * 256 + c4);
    uint2 q2 = *(const uint2*)(hm + (size_t)uu.z * 256 + c4);
    uint2 q3 = *(const uint2*)(hm + (size_t)uu.w * 256 + c4);
    half2v h0 = __builtin_bit_cast(half2v, q0.x), m0 = __builtin_bit_cast(half2v, q0.y);
    half2v h1 = __builtin_bit_cast(half2v, q1.x), m1 = __builtin_bit_cast(half2v, q1.y);
    half2v h2 = __builtin_bit_cast(half2v, q2.x), m2 = __builtin_bit_cast(half2v, q2.y);
    half2v h3 = __builtin_bit_cast(half2v, q3.x), m3 = __builtin_bit_cast(half2v, q3.y);
    sx += ((float)h0[0] + (float)h1[0]) + ((float)h2[0] + (float)h3[0]);
    sy += ((float)h0[1] + (float)h1[1]) + ((float)h2[1] + (float)h3[1]);
    msum = msum + (m0 + m1) + (m2 + m3);
  }
  for (; e < e1; ++e) {
    int u0 = esrc[e];
    uint2 q0 = *(const uint2*)(hm + (size_t)u0 * 256 + c4);
    half2v h0 = __builtin_bit_cast(half2v, q0.x), m0 = __builtin_bit_cast(half2v, q0.y);
    sx += (float)h0[0];
    sy += (float)h0[1];
    msum = msum + m0;
  }
  float2 so; so.x = sx; so.y = sy;
  *(float2*)&s[(size_t)v * DH + lane * 2] = so;
  *(half2v*)&mrh[(size_t)v * DH + lane * 2] = msum;
}

// ---------- K4: z/h_tilde GEMMs + gated update; reads s from d_out, overwrites with h_new
__global__ __launch_bounds__(256) void k4_update(
    const float* __restrict__ fsrc, const float* __restrict__ s,
    const _Float16* __restrict__ mrh, const _Float16* __restrict__ wf,
    const float* __restrict__ bz, const float* __restrict__ bb,
    float* __restrict__ out, int N) {
  const _Float16* wzf = wf + 0 * 16384;
  const _Float16* uzf = wf + 1 * 16384;
  const _Float16* wwf = wf + 4 * 16384;
  const _Float16* uuf = wf + 5 * 16384;
  int lane = threadIdx.x & 63, wid = threadIdx.x >> 6;
  int rowb = blockIdx.x * 64 + wid * 16;
  int mrow = lane & 15, g = lane >> 4;
  int arow = rowb + mrow; if (arow > N - 1) arow = N - 1;
  f32x4 az[8], ah[8];
#pragma unroll
  for (int i = 0; i < 8; ++i) {
    az[i] = (f32x4){0.f, 0.f, 0.f, 0.f};
    ah[i] = (f32x4){0.f, 0.f, 0.f, 0.f};
  }
  // phase 1: f_src contributes to both gates
#pragma unroll
  for (int kt = 0; kt < 4; ++kt) {
    half8 af = load_afrag(fsrc, arow, kt * 32 + g * 8);
#pragma unroll
    for (int nt = 0; nt < 8; ++nt) {
      half8 b0 = *(const half8*)&wzf[(kt * 8 + nt) * 512 + lane * 8];
      half8 b1 = *(const half8*)&wwf[(kt * 8 + nt) * 512 + lane * 8];
      az[nt] = __builtin_amdgcn_mfma_f32_16x16x32_f16(af, b0, az[nt], 0, 0, 0);
      ah[nt] = __builtin_amdgcn_mfma_f32_16x16x32_f16(af, b1, ah[nt], 0, 0, 0);
    }
  }
  // phase 2: s @ uz -> z gate
#pragma unroll
  for (int kt = 0; kt < 4; ++kt) {
    half8 af = load_afrag(s, arow, kt * 32 + g * 8);
#pragma unroll
    for (int nt = 0; nt < 8; ++nt) {
      half8 b0 = *(const half8*)&uzf[(kt * 8 + nt) * 512 + lane * 8];
      az[nt] = __builtin_amdgcn_mfma_f32_16x16x32_f16(af, b0, az[nt], 0, 0, 0);
    }
  }
  // phase 3: mrh @ u -> candidate (mrh fp16, direct frag load)
#pragma unroll
  for (int kt = 0; kt < 4; ++kt) {
    half8 af = load_afrag_h(mrh, arow, kt * 32 + g * 8);
#pragma unroll
    for (int nt = 0; nt < 8; ++nt) {
      half8 b1 = *(const half8*)&uuf[(kt * 8 + nt) * 512 + lane * 8];
      ah[nt] = __builtin_amdgcn_mfma_f32_16x16x32_f16(af, b1, ah[nt], 0, 0, 0);
    }
  }
  int orow = rowb + g * 4;
#pragma unroll
  for (int nt = 0; nt < 8; ++nt) {
    int col = nt * 16 + mrow;
    float bzc = bz[col], bbc = bb[col];
#pragma unroll
    for (int r = 0; r < 4; ++r) {
      int row = orow + r;
      if (row < N) {
        float zarg = az[nt][r] + bzc;
        float z = 1.f / (1.f + __expf(-zarg));
        float e2 = __expf(2.f * (ah[nt][r] + bbc));
        float th = (e2 - 1.f) / (e2 + 1.f);
        float sv = s[(size_t)row * DH + col];
        out[(size_t)row * DH + col] = (1.f - z) * sv + z * th;
      }
    }
  }
}

extern "C" void kernel_launch(void* const* d_in, const int* in_sizes, int n_in,
                              void* d_out, int out_size, void* d_ws, size_t ws_size,
                              hipStream_t stream) {
  const float* h    = (const float*)d_in[0];
  const float* fsrc = (const float*)d_in[1];
  const float* fdst = (const float*)d_in[2];
  const int*   src  = (const int*)d_in[3];
  const int*   dst  = (const int*)d_in[4];
  const float* wz   = (const float*)d_in[5];
  const float* uz   = (const float*)d_in[6];
  const float* bz   = (const float*)d_in[7];
  const float* wr   = (const float*)d_in[8];
  const float* ur   = (const float*)d_in[9];
  const float* br   = (const float*)d_in[10];
  const float* w    = (const float*)d_in[11];
  const float* u    = (const float*)d_in[12];
  const float* b    = (const float*)d_in[13];
  int N = in_sizes[0] / DH;
  int E = in_sizes[3];
  float* out = (float*)d_out;

  char* ws = (char*)d_ws;
  size_t o = 0;
  auto take = [&](size_t bytes) {
    char* p = ws + o;
    o = (o + bytes + 255) & ~(size_t)255;
    return p;
  };
  _Float16* wf     = (_Float16*)take(6 * 16384 * sizeof(_Float16));
  _Float16* hm     = (_Float16*)take((size_t)N * 256 * 2);  // interleaved h16|m16
  _Float16* mrh    = (_Float16*)take((size_t)N * DH * 2);
  int*      cnt    = (int*)take((size_t)N * 4);
  int*      offs   = (int*)take((size_t)(N + 1) * 4);
  int*      cursor = (int*)take((size_t)N * 4);
  int*      bsum   = (int*)take(4096);
  int*      esrc   = (int*)take((size_t)E * 4);

  int nb = (N + 255) / 256;  // 391 for N=100000; scan_bsums assumes nb <= 512

  pack_weights<<<(6 * 16384 + 255) / 256, 256, 0, stream>>>(wz, uz, wr, ur, w, u, wf);
  (void)hipMemsetAsync(cnt, 0, (size_t)N * 4, stream);
  count_deg<<<((E + 3) / 4 + 255) / 256, 256, 0, stream>>>(dst, cnt, E);
  block_reduce<<<nb, 256, 0, stream>>>(cnt, bsum, N);
  scan_bsums<<<1, 512, 0, stream>>>(bsum, nb, offs, N, E);
  scan_block<<<nb, 256, 0, stream>>>(cnt, bsum, offs, cursor, N);
  scatter_edges<<<(E + 255) / 256, 256, 0, stream>>>(src, dst, cursor, esrc, E);
  k1_node_gate<<<(N + 63) / 64, 256, 0, stream>>>(fdst, h, wf, br, hm, N);
  k3_gather<<<(N + 3) / 4, 256, 0, stream>>>(offs, esrc, hm, out, mrh, N);
  k4_update<<<(N + 63) / 64, 256, 0, stream>>>(fsrc, out, mrh, wf, bz, b, out, N);
}